// Round 15
// baseline (196.715 us; speedup 1.0000x reference)
//
#include <hip/hip_runtime.h>
#include <cstdint>

#define N 4096
#define D 1024
#define KC_COUNT (D / 32)    // 32 k-chunks of 32
#define TG (N / 64)          // 64 tile rows/cols of 64 (no padding)
#define NBLK (TG * (TG + 1) / 2)   // 2080 upper-triangular 64x64 tiles
#define BUFSZ (4 * 2 * 512)  // 4096 f16 = 8 KB per B buffer

typedef _Float16 f16;
typedef __attribute__((ext_vector_type(8))) _Float16 f16x8;
typedef __attribute__((ext_vector_type(4))) float f32x4;

// Monotone map fp32 -> u32 so unsigned compare == float compare (ascending).
__device__ __forceinline__ unsigned int orderable(float f) {
    unsigned int b = __float_as_uint(f);
    return (b & 0x80000000u) ? ~b : (b | 0x80000000u);
}

__device__ __forceinline__ void async_copy16(const f16* g, f16* l) {
    __builtin_amdgcn_global_load_lds(
        (const __attribute__((address_space(1))) uint32_t*)(const void*)g,
        (__attribute__((address_space(3))) uint32_t*)(void*)l,
        16 /*bytes*/, 0 /*offset*/, 0 /*aux*/);
}

// Direct fp32 -> f16 hi/lo split, written straight to MFMA fragment order
// (no LDS, no barriers). Validated round 11: -5.6 us vs LDS version.
__global__ __launch_bounds__(256) void split_direct(
    const float* __restrict__ X, f16* __restrict__ Xsw,
    unsigned long long* __restrict__ keys)
{
    const int tid = threadIdx.x;
    const int bid = blockIdx.x;
    const int rg = bid >> 2, kq = bid & 3;
    const int lane = tid & 63, w = tid >> 6;
    const int m = lane & 15, qq = lane >> 4;

    if (bid < 32) keys[bid * 256 + tid] = 0xFFFFFFFFFFFFFFFFull;

#pragma unroll
    for (int s = 0; s < 2; ++s) {
        const int kc = kq * 8 + w * 2 + s;   // 8 kc of this quarter over 4 waves
        f16x8 h, l;
        const float* src = X + (size_t)(rg * 16 + m) * D + kc * 32 + qq * 8;
        const float4 v0 = *(const float4*)src;
        const float4 v1 = *(const float4*)(src + 4);
        const float xs[8] = {v0.x, v0.y, v0.z, v0.w, v1.x, v1.y, v1.z, v1.w};
#pragma unroll
        for (int e = 0; e < 8; ++e) {
            const f16 hh = (f16)xs[e];
            h[e] = hh;
            l[e] = (f16)(xs[e] - (float)hh);
        }
        f16* dst = Xsw + ((size_t)(rg * KC_COUNT + kc) * 2) * 512 + lane * 8;
        *(f16x8*)dst = h;            // hl=0 plane
        *(f16x8*)(dst + 512) = l;    // hl=1 plane
    }
}

// 64x64 upper-triangular tile of dist = X @ X^T, 4 waves (2x2 of 32x32),
// f16-split MFMA (hi*hi + hi*lo + lo*hi), single-barrier ping-pong B
// double-buffer (2 x 8 KB) + A direct-to-register global loads.
// WHY 64^2: the gemm plateau (71-92 us across 5 schedules) tracked
// blocks/CU monotonically: 128^2=2.1/CU->92, 96^2=3.7/CU->71-74. The grid
// was the occupancy limiter (14.8 waves/CU, Occ 27-35%). 64^2 -> 2080
// blocks = 8.1/CU, ~24+ waves/CU resident: 2x the latency-hiding for the
// stage drains. No padding (4096=64x64); NBLK%8==0 -> simple XCD chunking.
__global__ __launch_bounds__(256, 6) void gemm_argmin_sym(
    const f16* __restrict__ Xsw, const int* __restrict__ labels,
    unsigned long long* __restrict__ keys_ap,
    unsigned long long* __restrict__ keys_an)
{
    __shared__ f16 Bs[2][BUFSZ];   // 16 KB ping-pong (B only)

    // T1 XCD-chunked remap (NBLK=2080 divisible by 8 -> simple form).
    const int b = blockIdx.x;
    const int wg = (b & 7) * (NBLK / 8) + (b >> 3);

    // Decode work id -> (ti, tj) with ti <= tj over TG=64.
    int r = wg, ti = 0;
    while (r >= TG - ti) { r -= TG - ti; ++ti; }
    const int tj = ti + r;

    const int tid = threadIdx.x;
    const int lane = tid & 63;
    const int w = tid >> 6;            // wave 0..3
    const int wr = w >> 1, wc = w & 1; // 2x2 wave grid, 32x32 region each
    const int rowBase = ti * 64, colBase = tj * 64;

    f32x4 acc[2][2];
#pragma unroll
    for (int mi = 0; mi < 2; ++mi)
#pragma unroll
        for (int ni = 0; ni < 2; ++ni) acc[mi][ni] = (f32x4){0.f, 0.f, 0.f, 0.f};

    // B staging: wave w stages chunks c = w*2, w*2+1 (8 total: 4rg x hi/lo).
    const f16* gB[2];
    f16* lpB[2];
#pragma unroll
    for (int j = 0; j < 2; ++j) {
        int c = w * 2 + j;
        int rgL = c >> 1, hl = c & 1;
        int rgG = tj * 4 + rgL;
        gB[j] = Xsw + ((((size_t)rgG * KC_COUNT) * 2 + hl) * 64 + lane) * 8;  // kc=0
        lpB[j] = Bs[0] + (rgL * 2 + hl) * 512;  // wave-uniform base (buf 0)
    }

    // A direct-load pointers: wave reads rows rgA = ti*4 + wr*2 + t2, hi/lo.
    const f16* gA[2][2];
#pragma unroll
    for (int t2 = 0; t2 < 2; ++t2) {
        int rgG = ti * 4 + wr * 2 + t2;
#pragma unroll
        for (int hl = 0; hl < 2; ++hl)
            gA[t2][hl] = Xsw + ((((size_t)rgG * KC_COUNT) * 2 + hl) * 64 + lane) * 8;
    }

    // Prologue: stage kc=0 into buf 0 (drains at the kc=0 barrier).
#pragma unroll
    for (int j = 0; j < 2; ++j)
        async_copy16(gB[j], lpB[j]);

    for (int kc = 0; kc < KC_COUNT; ++kc) {
        const size_t ko = (size_t)kc * 1024;
        const int cur = kc & 1;

        // A fragments for this step (compiler inserts vmcnt before use).
        f16x8 ah[2], al[2];
#pragma unroll
        for (int t2 = 0; t2 < 2; ++t2) {
            ah[t2] = *(const f16x8*)(gA[t2][0] + ko);
            al[t2] = *(const f16x8*)(gA[t2][1] + ko);
        }

        __syncthreads();   // drains stage(kc); confirms buf^1 readers done

        // Stage next tile into the other buffer: in flight across this
        // step's ds_read + 12 MFMAs + next step's A-loads (plus 5-7 other
        // resident blocks' compute at 8.1 blocks/CU).
        if (kc + 1 < KC_COUNT) {
#pragma unroll
            for (int j = 0; j < 2; ++j)
                async_copy16(gB[j] + ko + 1024, lpB[j] + (cur ^ 1) * BUFSZ);
        }

        f16x8 bh[2], bl[2];
#pragma unroll
        for (int t2 = 0; t2 < 2; ++t2) {
            int rgB = wc * 2 + t2;
            bh[t2] = *(const f16x8*)(Bs[cur] + (rgB * 2 + 0) * 512 + lane * 8);
            bl[t2] = *(const f16x8*)(Bs[cur] + (rgB * 2 + 1) * 512 + lane * 8);
        }
#pragma unroll
        for (int mi = 0; mi < 2; ++mi)
#pragma unroll
            for (int ni = 0; ni < 2; ++ni) {
                acc[mi][ni] = __builtin_amdgcn_mfma_f32_16x16x32_f16(
                    ah[mi], bh[ni], acc[mi][ni], 0, 0, 0);
                acc[mi][ni] = __builtin_amdgcn_mfma_f32_16x16x32_f16(
                    ah[mi], bl[ni], acc[mi][ni], 0, 0, 0);
                acc[mi][ni] = __builtin_amdgcn_mfma_f32_16x16x32_f16(
                    al[mi], bh[ni], acc[mi][ni], 0, 0, 0);
            }
    }

    // Epilogue. C/D layout (16x16): col = lane&15, row = (lane>>4)*4 + reg.
    // No padding: all i/j indices are in-range.
    const int g16 = lane >> 4, c16 = lane & 15;

    int ljv[2], liv[2][4];
#pragma unroll
    for (int ni = 0; ni < 2; ++ni)
        ljv[ni] = labels[colBase + wc * 32 + ni * 16 + c16];
#pragma unroll
    for (int mi = 0; mi < 2; ++mi)
#pragma unroll
        for (int reg = 0; reg < 4; ++reg)
            liv[mi][reg] = labels[rowBase + wr * 32 + mi * 16 + g16 * 4 + reg];

    // Pass 1: row-side argmin (rows of ti-range over cols of tj-range).
#pragma unroll
    for (int mi = 0; mi < 2; ++mi) {
#pragma unroll
        for (int reg = 0; reg < 4; ++reg) {
            const int i = rowBase + wr * 32 + mi * 16 + g16 * 4 + reg;
            const int li = liv[mi][reg];
            float bestAp = __builtin_huge_valf(); int jAp = 0;
            float bestAn = __builtin_huge_valf(); int jAn = 0;
#pragma unroll
            for (int ni = 0; ni < 2; ++ni) {
                const int jcol = colBase + wc * 32 + ni * 16 + c16;
                const float v = acc[mi][ni][reg];
                const bool same = (li == ljv[ni]);
                const float vap = (same && (i != jcol)) ? v : v + 2.0f;
                const float van = (!same) ? v : v + 2.0f;
                if (vap < bestAp) { bestAp = vap; jAp = jcol; }
                if (van < bestAn) { bestAn = van; jAn = jcol; }
            }
            unsigned long long kap =
                ((unsigned long long)orderable(bestAp) << 32) | (unsigned)jAp;
            unsigned long long kan =
                ((unsigned long long)orderable(bestAn) << 32) | (unsigned)jAn;
#pragma unroll
            for (int off = 1; off < 16; off <<= 1) {
                unsigned long long o = __shfl_xor(kap, off); kap = o < kap ? o : kap;
                o = __shfl_xor(kan, off); kan = o < kan ? o : kan;
            }
            if (c16 == 0) {
                atomicMin(&keys_ap[i], kap);
                atomicMin(&keys_an[i], kan);
            }
        }
    }

    // Pass 2 (off-diagonal only): column-side argmin via symmetry.
    if (ti != tj) {
#pragma unroll
        for (int ni = 0; ni < 2; ++ni) {
            const int j = colBase + wc * 32 + ni * 16 + c16;
            const int lj = ljv[ni];
            float bestAp = __builtin_huge_valf(); int iAp = 0;
            float bestAn = __builtin_huge_valf(); int iAn = 0;
#pragma unroll
            for (int mi = 0; mi < 2; ++mi)
#pragma unroll
                for (int reg = 0; reg < 4; ++reg) {
                    const int i = rowBase + wr * 32 + mi * 16 + g16 * 4 + reg;
                    const float v = acc[mi][ni][reg];
                    const bool same = (liv[mi][reg] == lj);
                    const float vap = same ? v : v + 2.0f;   // i != j off-diag
                    const float van = (!same) ? v : v + 2.0f;
                    if (vap < bestAp) { bestAp = vap; iAp = i; }
                    if (van < bestAn) { bestAn = van; iAn = i; }
                }
            unsigned long long kap =
                ((unsigned long long)orderable(bestAp) << 32) | (unsigned)iAp;
            unsigned long long kan =
                ((unsigned long long)orderable(bestAn) << 32) | (unsigned)iAn;
            // Reduce over g16 (lane bits 4,5): lanes sharing c16 share j.
#pragma unroll
            for (int off = 16; off < 64; off <<= 1) {
                unsigned long long o = __shfl_xor(kap, off); kap = o < kap ? o : kap;
                o = __shfl_xor(kan, off); kan = o < kan ? o : kan;
            }
            if (g16 == 0) {
                atomicMin(&keys_ap[j], kap);
                atomicMin(&keys_an[j], kan);
            }
        }
    }
}

__global__ void gather_rows(const float* __restrict__ A,
                            const unsigned long long* __restrict__ keys_ap,
                            const unsigned long long* __restrict__ keys_an,
                            float* __restrict__ out)
{
    const int row = blockIdx.x;
    const int t = threadIdx.x;
    const int ja = (int)(keys_ap[row] & 0xFFFFFFFFull);
    const int jn = (int)(keys_an[row] & 0xFFFFFFFFull);
    const float4* Av = (const float4*)A;
    float4* Ov = (float4*)out;
    Ov[(size_t)row * (D / 4) + t]       = Av[(size_t)ja * (D / 4) + t];
    Ov[(size_t)(N + row) * (D / 4) + t] = Av[(size_t)jn * (D / 4) + t];
}

extern "C" void kernel_launch(void* const* d_in, const int* in_sizes, int n_in,
                              void* d_out, int out_size, void* d_ws, size_t ws_size,
                              hipStream_t stream) {
    const float* A = (const float*)d_in[0];
    const int* labels = (const int*)d_in[1];  // integer inputs arrive as int32
    float* out = (float*)d_out;

    unsigned long long* keys = (unsigned long long*)d_ws;          // 64 KB
    f16* Xsw = (f16*)((char*)d_ws + 65536);   // 256 rg * 64 KB = 16 MB hi+lo

    split_direct<<<256 * 4, 256, 0, stream>>>(A, Xsw, keys);
    gemm_argmin_sym<<<NBLK, 256, 0, stream>>>(Xsw, labels, keys, keys + N);
    gather_rows<<<N, 256, 0, stream>>>(A, keys, keys + N, out);
}

// Round 18
// 149.764 us; speedup vs baseline: 1.3135x; 1.3135x over previous
//
#include <hip/hip_runtime.h>
#include <cstdint>

#define N 4096
#define D 1024
#define KC_COUNT (D / 32)    // 32 k-chunks of 32
#define NP 4128              // N padded to a multiple of 96
#define TG (NP / 96)         // 43 tile rows/cols of 96
#define NBLK (TG * (TG + 1) / 2)   // 946 upper-triangular 96x96 tiles
#define BUFSZ (6 * 2 * 512)  // 6144 f16 = 12 KB per B buffer

typedef _Float16 f16;
typedef __attribute__((ext_vector_type(8))) _Float16 f16x8;
typedef __attribute__((ext_vector_type(4))) float f32x4;

// Monotone map fp32 -> u32 so unsigned compare == float compare (ascending).
__device__ __forceinline__ unsigned int orderable(float f) {
    unsigned int b = __float_as_uint(f);
    return (b & 0x80000000u) ? ~b : (b | 0x80000000u);
}

__device__ __forceinline__ void async_copy16(const f16* g, f16* l) {
    __builtin_amdgcn_global_load_lds(
        (const __attribute__((address_space(1))) uint32_t*)(const void*)g,
        (__attribute__((address_space(3))) uint32_t*)(void*)l,
        16 /*bytes*/, 0 /*offset*/, 0 /*aux*/);
}

// Direct fp32 -> f16 hi/lo split, written straight to MFMA fragment order
// (no LDS, no barriers). Validated round 11: -5.6 us vs LDS version.
__global__ __launch_bounds__(256) void split_direct(
    const float* __restrict__ X, f16* __restrict__ Xsw,
    unsigned long long* __restrict__ keys)
{
    const int tid = threadIdx.x;
    const int bid = blockIdx.x;
    const int rg = bid >> 2, kq = bid & 3;
    const int lane = tid & 63, w = tid >> 6;
    const int m = lane & 15, qq = lane >> 4;

    if (bid < 32) keys[bid * 256 + tid] = 0xFFFFFFFFFFFFFFFFull;

#pragma unroll
    for (int s = 0; s < 2; ++s) {
        const int kc = kq * 8 + w * 2 + s;   // 8 kc of this quarter over 4 waves
        f16x8 h = (f16x8)(f16)0, l = (f16x8)(f16)0;
        if (rg < 256) {
            const float* src = X + (size_t)(rg * 16 + m) * D + kc * 32 + qq * 8;
            const float4 v0 = *(const float4*)src;
            const float4 v1 = *(const float4*)(src + 4);
            const float xs[8] = {v0.x, v0.y, v0.z, v0.w, v1.x, v1.y, v1.z, v1.w};
#pragma unroll
            for (int e = 0; e < 8; ++e) {
                const f16 hh = (f16)xs[e];
                h[e] = hh;
                l[e] = (f16)(xs[e] - (float)hh);
            }
        }
        f16* dst = Xsw + ((size_t)(rg * KC_COUNT + kc) * 2) * 512 + lane * 8;
        *(f16x8*)dst = h;            // hl=0 plane
        *(f16x8*)(dst + 512) = l;    // hl=1 plane
    }
}

// 96x96 upper-triangular tile of dist = X @ X^T, 4 waves (2x2 of 48x48),
// f16-split MFMA (hi*hi + hi*lo + lo*hi).
// MEASURED-BEST configuration (round 13): single-barrier ping-pong B
// double-buffer (2 x 12 KB) + A direct-to-register global loads + T1
// XCD-chunked swizzle. gemm 71.4 us. Full design-space sweep around it:
//   tile:    64^2=122us (staging-BW bound), 96^2=71-74, 128^2=92 (occ bound)
//   sched:   2-barrier 73-74, counted-vmcnt 77, ping-pong 71.4
//   ops:     A-via-LDS == A-direct (neutral); coop-fusion broken (capture)
// Every neighbor is worse: this is the plateau point.
__global__ __launch_bounds__(256, 4) void gemm_argmin_sym(
    const f16* __restrict__ Xsw, const int* __restrict__ labels,
    unsigned long long* __restrict__ keys_ap,
    unsigned long long* __restrict__ keys_an)
{
    __shared__ f16 Bs[2][BUFSZ];   // 24 KB ping-pong (B only)

    // T1 XCD-chunked bijective remap (kept: FETCH-neutral-or-better).
    const int b = blockIdx.x;
    const int xcd = b & 7;
    const int q = NBLK >> 3, rem = NBLK & 7;   // 118, 2
    const int wg = (xcd < rem ? xcd * (q + 1)
                              : rem * (q + 1) + (xcd - rem) * q) + (b >> 3);

    // Decode work id -> (ti, tj) with ti <= tj over TG=43.
    int r = wg, ti = 0;
    while (r >= TG - ti) { r -= TG - ti; ++ti; }
    const int tj = ti + r;

    const int tid = threadIdx.x;
    const int lane = tid & 63;
    const int w = tid >> 6;            // wave 0..3
    const int wr = w >> 1, wc = w & 1; // 2x2 wave grid, 48x48 region each
    const int rowBase = ti * 96, colBase = tj * 96;

    f32x4 acc[3][3];
#pragma unroll
    for (int mi = 0; mi < 3; ++mi)
#pragma unroll
        for (int ni = 0; ni < 3; ++ni) acc[mi][ni] = (f32x4){0.f, 0.f, 0.f, 0.f};

    // B staging: wave w stages chunks c = w*3 .. w*3+2 (12 total: 6rg x hi/lo).
    const f16* gB[3];
    f16* lpB[3];
#pragma unroll
    for (int j = 0; j < 3; ++j) {
        int c = w * 3 + j;
        int rgL = c >> 1, hl = c & 1;
        int rgG = tj * 6 + rgL;
        gB[j] = Xsw + ((((size_t)rgG * KC_COUNT) * 2 + hl) * 64 + lane) * 8;  // kc=0
        lpB[j] = Bs[0] + (rgL * 2 + hl) * 512;  // wave-uniform base (buf 0)
    }

    // A direct-load pointers: wave reads rows rgA = ti*6 + wr*3 + t2, hi/lo.
    const f16* gA[3][2];
#pragma unroll
    for (int t2 = 0; t2 < 3; ++t2) {
        int rgG = ti * 6 + wr * 3 + t2;
#pragma unroll
        for (int hl = 0; hl < 2; ++hl)
            gA[t2][hl] = Xsw + ((((size_t)rgG * KC_COUNT) * 2 + hl) * 64 + lane) * 8;
    }

    // Prologue: stage kc=0 into buf 0 (drains at the kc=0 barrier).
#pragma unroll
    for (int j = 0; j < 3; ++j)
        async_copy16(gB[j], lpB[j]);

    for (int kc = 0; kc < KC_COUNT; ++kc) {
        const size_t ko = (size_t)kc * 1024;
        const int cur = kc & 1;

        // A fragments for this step (plain global loads; compiler inserts
        // the vmcnt wait before first MFMA use).
        f16x8 ah[3], al[3];
#pragma unroll
        for (int t2 = 0; t2 < 3; ++t2) {
            ah[t2] = *(const f16x8*)(gA[t2][0] + ko);
            al[t2] = *(const f16x8*)(gA[t2][1] + ko);
        }

        __syncthreads();   // drains stage(kc); confirms buf^1 readers done

        // Stage next tile into the other buffer: in flight across this
        // step's ds_read + 27 MFMAs + next step's A-loads.
        if (kc + 1 < KC_COUNT) {
#pragma unroll
            for (int j = 0; j < 3; ++j)
                async_copy16(gB[j] + ko + 1024, lpB[j] + (cur ^ 1) * BUFSZ);
        }

        f16x8 bh[3], bl[3];
#pragma unroll
        for (int t2 = 0; t2 < 3; ++t2) {
            int rgB = wc * 3 + t2;
            bh[t2] = *(const f16x8*)(Bs[cur] + (rgB * 2 + 0) * 512 + lane * 8);
            bl[t2] = *(const f16x8*)(Bs[cur] + (rgB * 2 + 1) * 512 + lane * 8);
        }
#pragma unroll
        for (int mi = 0; mi < 3; ++mi)
#pragma unroll
            for (int ni = 0; ni < 3; ++ni) {
                acc[mi][ni] = __builtin_amdgcn_mfma_f32_16x16x32_f16(
                    ah[mi], bh[ni], acc[mi][ni], 0, 0, 0);
                acc[mi][ni] = __builtin_amdgcn_mfma_f32_16x16x32_f16(
                    ah[mi], bl[ni], acc[mi][ni], 0, 0, 0);
                acc[mi][ni] = __builtin_amdgcn_mfma_f32_16x16x32_f16(
                    al[mi], bh[ni], acc[mi][ni], 0, 0, 0);
            }
    }

    // Epilogue. C/D layout (16x16): col = lane&15, row = (lane>>4)*4 + reg.
    const int g16 = lane >> 4, c16 = lane & 15;

    int ljv[3], liv[3][4];
#pragma unroll
    for (int ni = 0; ni < 3; ++ni) {
        const int j = colBase + wc * 48 + ni * 16 + c16;
        ljv[ni] = (j < N) ? labels[j] : -1;    // pad sentinel: matches nothing
    }
#pragma unroll
    for (int mi = 0; mi < 3; ++mi)
#pragma unroll
        for (int reg = 0; reg < 4; ++reg) {
            const int i = rowBase + wr * 48 + mi * 16 + g16 * 4 + reg;
            liv[mi][reg] = (i < N) ? labels[i] : -1;
        }

    // Pass 1: row-side argmin (rows of ti-range over cols of tj-range).
#pragma unroll
    for (int mi = 0; mi < 3; ++mi) {
#pragma unroll
        for (int reg = 0; reg < 4; ++reg) {
            const int i = rowBase + wr * 48 + mi * 16 + g16 * 4 + reg;
            const int li = liv[mi][reg];
            float bestAp = __builtin_huge_valf(); int jAp = 0;
            float bestAn = __builtin_huge_valf(); int jAn = 0;
#pragma unroll
            for (int ni = 0; ni < 3; ++ni) {
                const int jcol = colBase + wc * 48 + ni * 16 + c16;
                const float v = acc[mi][ni][reg];
                const bool same = (li == ljv[ni]);
                const float vap = (same && (i != jcol)) ? v : v + 2.0f;
                const float van = (!same) ? v : v + 2.0f;
                if (vap < bestAp) { bestAp = vap; jAp = jcol; }
                if (van < bestAn) { bestAn = van; jAn = jcol; }
            }
            unsigned long long kap =
                ((unsigned long long)orderable(bestAp) << 32) | (unsigned)jAp;
            unsigned long long kan =
                ((unsigned long long)orderable(bestAn) << 32) | (unsigned)jAn;
#pragma unroll
            for (int off = 1; off < 16; off <<= 1) {
                unsigned long long o = __shfl_xor(kap, off); kap = o < kap ? o : kap;
                o = __shfl_xor(kan, off); kan = o < kan ? o : kan;
            }
            if (c16 == 0 && i < N) {
                atomicMin(&keys_ap[i], kap);
                atomicMin(&keys_an[i], kan);
            }
        }
    }

    // Pass 2 (off-diagonal only): column-side argmin via symmetry.
    if (ti != tj) {
#pragma unroll
        for (int ni = 0; ni < 3; ++ni) {
            const int j = colBase + wc * 48 + ni * 16 + c16;
            const int lj = ljv[ni];
            float bestAp = __builtin_huge_valf(); int iAp = 0;
            float bestAn = __builtin_huge_valf(); int iAn = 0;
#pragma unroll
            for (int mi = 0; mi < 3; ++mi)
#pragma unroll
                for (int reg = 0; reg < 4; ++reg) {
                    const int i = rowBase + wr * 48 + mi * 16 + g16 * 4 + reg;
                    const float v = acc[mi][ni][reg];
                    // pad rows have label -1 != lj -> negative, v = 0: never wins
                    const bool same = (liv[mi][reg] == lj);
                    const float vap = same ? v : v + 2.0f;   // i != j off-diag
                    const float van = (!same) ? v : v + 2.0f;
                    if (vap < bestAp) { bestAp = vap; iAp = i; }
                    if (van < bestAn) { bestAn = van; iAn = i; }
                }
            unsigned long long kap =
                ((unsigned long long)orderable(bestAp) << 32) | (unsigned)iAp;
            unsigned long long kan =
                ((unsigned long long)orderable(bestAn) << 32) | (unsigned)iAn;
            // Reduce over g16 (lane bits 4,5): lanes sharing c16 share j.
#pragma unroll
            for (int off = 16; off < 64; off <<= 1) {
                unsigned long long o = __shfl_xor(kap, off); kap = o < kap ? o : kap;
                o = __shfl_xor(kan, off); kan = o < kan ? o : kan;
            }
            if (g16 == 0 && j < N) {
                atomicMin(&keys_ap[j], kap);
                atomicMin(&keys_an[j], kan);
            }
        }
    }
}

__global__ void gather_rows(const float* __restrict__ A,
                            const unsigned long long* __restrict__ keys_ap,
                            const unsigned long long* __restrict__ keys_an,
                            float* __restrict__ out)
{
    const int row = blockIdx.x;
    const int t = threadIdx.x;
    const int ja = (int)(keys_ap[row] & 0xFFFFFFFFull);
    const int jn = (int)(keys_an[row] & 0xFFFFFFFFull);
    const float4* Av = (const float4*)A;
    float4* Ov = (float4*)out;
    Ov[(size_t)row * (D / 4) + t]       = Av[(size_t)ja * (D / 4) + t];
    Ov[(size_t)(N + row) * (D / 4) + t] = Av[(size_t)jn * (D / 4) + t];
}

extern "C" void kernel_launch(void* const* d_in, const int* in_sizes, int n_in,
                              void* d_out, int out_size, void* d_ws, size_t ws_size,
                              hipStream_t stream) {
    const float* A = (const float*)d_in[0];
    const int* labels = (const int*)d_in[1];  // integer inputs arrive as int32
    float* out = (float*)d_out;

    unsigned long long* keys = (unsigned long long*)d_ws;          // 64 KB
    f16* Xsw = (f16*)((char*)d_ws + 65536);   // 258 rg * 64 KB = 16.9 MB hi+lo

    split_direct<<<258 * 4, 256, 0, stream>>>(A, Xsw, keys);
    gemm_argmin_sym<<<NBLK, 256, 0, stream>>>(Xsw, labels, keys, keys + N);
    gather_rows<<<N, 256, 0, stream>>>(A, keys, keys + N, out);
}